// Round 11
// baseline (620.001 us; speedup 1.0000x reference)
//
#include <hip/hip_runtime.h>
#include <hip/hip_cooperative_groups.h>
#include <stdint.h>

namespace cg = cooperative_groups;

#define B_ 1024
#define D_ 784
#define H_ 1024
#define BH_ (B_ * H_)
#define LOG2E 1.4426950408889634f

// R11: single cooperative kernel = phase A {G-matmul (768 tasks, verified) +
// direct dual-half pack (400 tasks -> VWf bit-identical to v5 layout, no WT)}
// -> threadfence + grid.sync -> phase C = v5 scan (verified, 52 VGPR).
// Kills both inter-kernel gaps (~20us) + WT round-trip (~10us) of R10.
// mode 2 = cooperative fused; fallback (capture-time error) mode 0 (tasks,
// 1168 blocks) + mode 1 (scan, 1024 blocks) on the same kernel.
// Segments {0,200,392,592,784}; G [3][B][H] positive log2 domain; An negated.
// VWf image = 8 planes x 256 f32: planes 0-3 V, 4-7 -W*log2e; pair k=(h,h+512)
// at plane ((k&7)>>1), offset (k>>3)*4+(k&1)*2+comp.
// ws: VWf [788][2048] f32 6.46 MB | G [3][B][H] 12.6 MB

typedef float v2f __attribute__((ext_vector_type(2)));

__device__ __forceinline__ int seg_bound(int s) {
    const int b[5] = {0, 200, 392, 592, 784};
    return b[s];
}

// ---------- DPP reduce: full 64-lane sum into lane 63 ----------
template <int CTRL>
__device__ __forceinline__ float dpp_add(float p) {
    int s = __builtin_amdgcn_update_dpp(0, __float_as_int(p), CTRL, 0xf, 0xf, true);
    return p + __int_as_float(s);
}
__device__ __forceinline__ float reduce64(float p) {
    p = dpp_add<0x111>(p);   // row_shr:1
    p = dpp_add<0x112>(p);   // row_shr:2
    p = dpp_add<0x114>(p);   // row_shr:4
    p = dpp_add<0x118>(p);   // row_shr:8
    p = dpp_add<0x142>(p);   // row_bcast:15 -> lane31 = sum(0..31), lane63 = sum(32..63)
    p = dpp_add<0x143>(p);   // row_bcast:31 -> lane63 = sum(0..63)
    return p;
}

// Fused dual 8-wide rational tree on memory-native float2 pairs (v5, verified).
__device__ __forceinline__ void tree16(v2f (&An)[8], const float4 (&Va)[4], const float4 (&Wa)[4],
                                       float xi, v2f& n, v2f& d) {
    const v2f* va = (const v2f*)&Va[0];
    const v2f* wa = (const v2f*)&Wa[0];
    const v2f one = {1.f, 1.f};
    const v2f clamp15 = {15.f, 15.f};
    v2f xiv; xiv.x = xi; xiv.y = xi;
    v2f q[8];
#pragma unroll
    for (int k = 0; k < 8; ++k) {
        v2f m = __builtin_elementwise_min(clamp15, An[k]);   // v_pk_min_f32
        v2f e;
        e.x = __builtin_amdgcn_exp2f(m.x);
        e.y = __builtin_amdgcn_exp2f(m.y);
        q[k] = one + e;                 // v_pk_add_f32
        An[k] = wa[k] * xiv + An[k];    // v_pk_fma_f32 (W pre-negated)
    }
    v2f a01 = va[0] * q[1] + va[1] * q[0];
    v2f a23 = va[2] * q[3] + va[3] * q[2];
    v2f a45 = va[4] * q[5] + va[5] * q[4];
    v2f a67 = va[6] * q[7] + va[7] * q[6];
    v2f q01 = q[0] * q[1], q23 = q[2] * q[3];
    v2f q45 = q[4] * q[5], q67 = q[6] * q[7];
    v2f n0123 = a01 * q23 + a23 * q01;
    v2f n4567 = a45 * q67 + a67 * q45;
    v2f q0123 = q01 * q23, q4567 = q45 * q67;
    d = q0123 * q4567;
    n = n0123 * q4567 + n4567 * q0123;
}

// mode: 2 = cooperative fused; 0 = tasks only; 1 = scan only
__global__ __launch_bounds__(256, 4) void nade_fused(
    const float* __restrict__ px,            // [B, D]
    const float* __restrict__ W,             // [H, D]
    const float* __restrict__ c,             // [H]
    const float* __restrict__ V,             // [D, H]
    const float* __restrict__ bias,          // [D]
    float* __restrict__ VWf,                 // [788][2048] f32
    float* __restrict__ G,                   // [3][B][H]
    float* __restrict__ out,                 // [B, D]
    int mode)
{
    __shared__ float smem[4224];
    const int t   = threadIdx.x;
    const int bid = blockIdx.x;

    // ================= phase A: 768 gmm tasks + 400 pack tasks =================
    if (mode != 1) {
        for (int task = bid; task < 1168; task += gridDim.x) {
            __syncthreads();                  // protect smem reuse across tasks
            if (task < 768) {
                // ---- G matmul 64x64 tile (verified code) ----
                float* xs = smem;          // [8][64]
                float* ws = smem + 512;    // [8][64]
                int idx = task;
                int r   = idx >> 8;                       // 0..2
                int b0  = (idx & 15) * 64;
                int h0  = ((idx >> 4) & 15) * 64;
                int j0s = seg_bound(r), j1s = seg_bound(r + 1);

                const int tb = t >> 4, th = t & 15;       // 16x16, each 4b x 4h
                float acc[4][4];
#pragma unroll
                for (int bi = 0; bi < 4; ++bi)
#pragma unroll
                    for (int hh = 0; hh < 4; ++hh) acc[bi][hh] = 0.f;

                const int xb = t >> 3;                    // 0..31
                const int xj = t & 7;                     // 0..7
                const int wh = t >> 1, wj = (t & 1) * 4;  // for t < 128

                for (int j0 = j0s; j0 < j1s; j0 += 8) {
                    float xv0 = px[(size_t)(b0 + xb) * D_ + j0 + xj];
                    float xv1 = px[(size_t)(b0 + 32 + xb) * D_ + j0 + xj];
                    float4 wv = make_float4(0, 0, 0, 0);
                    if (t < 128) wv = *(const float4*)(W + (size_t)(h0 + wh) * D_ + j0 + wj);
                    __syncthreads();
                    xs[xj * 64 + xb]      = xv0;
                    xs[xj * 64 + 32 + xb] = xv1;
                    if (t < 128) {
                        ws[(wj + 0) * 64 + wh] = wv.x * LOG2E;   // G POSITIVE log2 domain
                        ws[(wj + 1) * 64 + wh] = wv.y * LOG2E;
                        ws[(wj + 2) * 64 + wh] = wv.z * LOG2E;
                        ws[(wj + 3) * 64 + wh] = wv.w * LOG2E;
                    }
                    __syncthreads();
#pragma unroll
                    for (int jj = 0; jj < 8; ++jj) {
                        float4 xq = *(float4*)&xs[jj * 64 + tb * 4];
                        float4 wq = *(float4*)&ws[jj * 64 + th * 4];
                        float xa[4] = {xq.x, xq.y, xq.z, xq.w};
                        float wa[4] = {wq.x, wq.y, wq.z, wq.w};
#pragma unroll
                        for (int bi = 0; bi < 4; ++bi)
#pragma unroll
                            for (int hh = 0; hh < 4; ++hh)
                                acc[bi][hh] = fmaf(xa[bi], wa[hh], acc[bi][hh]);
                    }
                }
                float* dst = G + (size_t)r * BH_;
#pragma unroll
                for (int bi = 0; bi < 4; ++bi) {
                    float4 o = make_float4(acc[bi][0], acc[bi][1], acc[bi][2], acc[bi][3]);
                    *(float4*)(dst + (size_t)(b0 + tb * 4 + bi) * H_ + h0 + th * 4) = o;
                }
            } else {
                // ---- dual-half pack task: 32 images x 32 h-pairs -> VWf ----
                int pt = task - 768;           // 0..399
                int i0 = (pt % 25) * 32;
                int h0 = (pt / 25) * 32;       // [0,512)
                float* smW = smem;             // [2][32][33]  (W^T: [h_local][i_local])
                float* smV = smem + 2112;      // [2][32][33]  (V:   [i_local][h_local])
                const int tx = t & 31, ty = t >> 5;
#pragma unroll
                for (int u = 0; u < 2; ++u)
#pragma unroll
                    for (int j = 0; j < 4; ++j) {
                        int rl = ty + j * 8;   // 0..31
                        float w = 0.f;
                        int iw = i0 + tx;
                        if (iw < D_) w = W[(size_t)(h0 + u * 512 + rl) * D_ + iw] * -LOG2E;
                        smW[u * 1056 + rl * 33 + tx] = w;
                        float v = 0.f;
                        int iv = i0 + rl;
                        if (iv < D_) v = V[(size_t)iv * H_ + h0 + u * 512 + tx];
                        smV[u * 1056 + rl * 33 + tx] = v;
                    }
                __syncthreads();
                const int img = t >> 3;
                const int iw  = i0 + img;
                if (iw < D_) {
                    const int sub = t & 7;
                    const int sp  = sub >> 1;  // plane 0..3
                    const int q   = sub & 1;   // half of 16-float chunk
                    float vv[8], wv[8];
#pragma unroll
                    for (int e = 0; e < 8; ++e) {
                        int p = q * 8 + e;                 // 0..15 chunk offset
                        int m = p >> 2, par = (p >> 1) & 1, comp = p & 1;
                        int hl = 8 * m + sp * 2 + par;     // 0..31
                        wv[e] = smW[comp * 1056 + hl * 33 + img];
                        vv[e] = smV[comp * 1056 + img * 33 + hl];
                    }
                    float* dst = VWf + (size_t)iw * 2048;
                    int cb = h0 / 2 + q * 8;
                    *(float4*)(dst + sp * 256 + cb)           = make_float4(vv[0], vv[1], vv[2], vv[3]);
                    *(float4*)(dst + sp * 256 + cb + 4)       = make_float4(vv[4], vv[5], vv[6], vv[7]);
                    *(float4*)(dst + (4 + sp) * 256 + cb)     = make_float4(wv[0], wv[1], wv[2], wv[3]);
                    *(float4*)(dst + (4 + sp) * 256 + cb + 4) = make_float4(wv[4], wv[5], wv[6], wv[7]);
                }
            }
        }
    }

    if (mode == 2) {
        __threadfence();                 // device-scope: publish G/VWf across XCDs
        cg::this_grid().sync();
        __threadfence();                 // acquire side
    }
    if (mode == 0) return;

    // ================= phase C: v5 scan (verified) =================
    {
        const int lane = t & 63;
        const int wid  = t >> 6;
        const int s    = (bid >> 1) & 3;         // xcd = bid&7 -> one segment per XCD
        const int rb   = ((bid >> 3) << 1) | (bid & 1);   // 0..255
        const int row  = rb * 4 + wid;

        const int i0s = seg_bound(s), i1s = seg_bound(s + 1);

        const int hA = lane * 8;
        const int hB = 512 + hA;

        v2f An[8];
        {
            float4 c0 = *(const float4*)(c + hA);
            float4 c1 = *(const float4*)(c + hA + 4);
            float4 c2 = *(const float4*)(c + hB);
            float4 c3 = *(const float4*)(c + hB + 4);
            An[0].x = -c0.x * LOG2E; An[0].y = -c2.x * LOG2E;
            An[1].x = -c0.y * LOG2E; An[1].y = -c2.y * LOG2E;
            An[2].x = -c0.z * LOG2E; An[2].y = -c2.z * LOG2E;
            An[3].x = -c0.w * LOG2E; An[3].y = -c2.w * LOG2E;
            An[4].x = -c1.x * LOG2E; An[4].y = -c3.x * LOG2E;
            An[5].x = -c1.y * LOG2E; An[5].y = -c3.y * LOG2E;
            An[6].x = -c1.z * LOG2E; An[6].y = -c3.z * LOG2E;
            An[7].x = -c1.w * LOG2E; An[7].y = -c3.w * LOG2E;
            for (int r = 0; r < s; ++r) {
                const float* gp = G + (size_t)r * BH_ + (size_t)row * H_;
                float4 g0 = *(const float4*)(gp + hA);
                float4 g1 = *(const float4*)(gp + hA + 4);
                float4 g2 = *(const float4*)(gp + hB);
                float4 g3 = *(const float4*)(gp + hB + 4);
                An[0].x -= g0.x; An[0].y -= g2.x;
                An[1].x -= g0.y; An[1].y -= g2.y;
                An[2].x -= g0.z; An[2].y -= g2.z;
                An[3].x -= g0.w; An[3].y -= g2.w;
                An[4].x -= g1.x; An[4].y -= g3.x;
                An[5].x -= g1.y; An[5].y -= g3.y;
                An[6].x -= g1.z; An[6].y -= g3.z;
                An[7].x -= g1.w; An[7].y -= g3.w;
            }
        }

        const float* xp = px + (size_t)row * D_;
        const float* vp = VWf + (size_t)i0s * 2048 + lane * 4;

        float4 VaC[4], WaC[4];
#pragma unroll
        for (int u = 0; u < 4; ++u) {
            VaC[u] = *(const float4*)(vp + u * 256);
            WaC[u] = *(const float4*)(vp + 1024 + u * 256);
        }
        vp += 2048;
        float4 xq = *(const float4*)(xp + i0s);

        for (int ib = i0s; ib < i1s; ib += 4) {
            int xb = (ib + 4 < i1s) ? (ib + 4) : i0s;
            float4 xq_n = *(const float4*)(xp + xb);
            float xa[4] = {xq.x, xq.y, xq.z, xq.w};
            float pr[4];
#pragma unroll
            for (int j = 0; j < 4; ++j) {
                float4 VaN[4], WaN[4];           // prefetch next (images padded past 784)
#pragma unroll
                for (int u = 0; u < 4; ++u) {
                    VaN[u] = *(const float4*)(vp + u * 256);
                    WaN[u] = *(const float4*)(vp + 1024 + u * 256);
                }
                vp += 2048;
                v2f n, d;
                tree16(An, VaC, WaC, xa[j], n, d);
                float p = fmaf(n.x, __builtin_amdgcn_rcpf(d.x),
                               n.y * __builtin_amdgcn_rcpf(d.y));
                pr[j] = reduce64(p);
#pragma unroll
                for (int u = 0; u < 4; ++u) { VaC[u] = VaN[u]; WaC[u] = WaN[u]; }
            }
            float4 b4 = *(const float4*)(bias + ib);
            if (lane == 63) {
                float4 o = make_float4(pr[0] + b4.x, pr[1] + b4.y, pr[2] + b4.z, pr[3] + b4.w);
                *(float4*)(out + (size_t)row * D_ + ib) = o;
            }
            xq = xq_n;
        }
    }
}

extern "C" void kernel_launch(void* const* d_in, const int* in_sizes, int n_in,
                              void* d_out, int out_size, void* d_ws, size_t ws_size,
                              hipStream_t stream) {
    const float* px   = (const float*)d_in[0];  // [B, D]
    const float* W    = (const float*)d_in[1];  // [H, D]
    const float* c    = (const float*)d_in[2];  // [H]
    const float* V    = (const float*)d_in[3];  // [D, H]
    const float* bias = (const float*)d_in[4];  // [D]
    float* out = (float*)d_out;                 // [B, D]

    float* VWf = (float*)d_ws;                                 // 788*2048 f32 = 6.46 MB
    float* G   = (float*)((char*)d_ws + (size_t)788 * 8192);   // [3][B][H] 12.6 MB

    int mode = 2;
    void* args[9] = {(void*)&px, (void*)&W, (void*)&c, (void*)&V, (void*)&bias,
                     (void*)&VWf, (void*)&G, (void*)&out, (void*)&mode};
    hipError_t err = hipLaunchCooperativeKernel(nade_fused, dim3(1024), dim3(256),
                                                args, 0u, stream);
    if (err != hipSuccess) {
        (void)hipGetLastError();   // clear error state; fall back to 2-launch path
        nade_fused<<<dim3(1168), 256, 0, stream>>>(px, W, c, V, bias, VWf, G, out, 0);
        nade_fused<<<dim3(1024), 256, 0, stream>>>(px, W, c, V, bias, VWf, G, out, 1);
    }
}